// Round 1
// baseline (105.048 us; speedup 1.0000x reference)
//
#include <hip/hip_runtime.h>
#include <math.h>

constexpr int B = 4, C = 64, H = 80, W = 80;
constexpr int HW = H * W;            // 6400
constexpr int NPIX = B * HW;         // 25600

static __device__ __forceinline__ float silu(float v) {
    float e = __expf(-v);
    return v * __builtin_amdgcn_rcpf(1.0f + e);
}

// ---------------------------------------------------------------------------
// Kernel 1: GLCM features. thread = (pixel, group of 4 channels).
// block: 256 threads = 16 pixels x 16 channel-groups. grid = 25600/16 = 1600.
// Writes g (B,4,H,W) f32.
// ---------------------------------------------------------------------------
__global__ __launch_bounds__(256) void glcm_kernel(const float* __restrict__ x,
                                                   float* __restrict__ g) {
    const int t = threadIdx.x;
    const int pxl = t & 15;
    const int cg  = t >> 4;                  // 0..15
    const int pix = blockIdx.x * 16 + pxl;   // 0..25599
    const int b   = pix / HW;
    const int hw  = pix - b * HW;
    const int h   = hw / W;
    const int w   = hw - h * W;
    // edge padding -> clamped neighbor coords
    const int hm = h > 0 ? h - 1 : 0;
    const int hp = h < H - 1 ? h + 1 : H - 1;
    const int wm = w > 0 ? w - 1 : 0;
    const int wp = w < W - 1 ? w + 1 : W - 1;
    const int r0 = hm * W, r1 = h * W, r2 = hp * W;

    const float* xb = x + (size_t)(b * C) * HW;

    // 20 co-occurrence pairs over the 3x3 patch (cells 0..8), 4 directions
    static constexpr int PA[20] = {0,1,3,4,6,7, 0,1,2,3,4,5, 0,1,3,4, 1,2,4,5};
    static constexpr int PB[20] = {1,2,4,5,7,8, 3,4,5,6,7,8, 4,5,7,8, 3,4,6,7};

    int   csum = 0, esum = 0;
    float hsum = 0.f, lsum = 0.f;

    for (int ci = 0; ci < 4; ++ci) {
        const float* xc = xb + (size_t)(cg * 4 + ci) * HW;
        float v[9];
        v[0] = xc[r0 + wm]; v[1] = xc[r0 + w]; v[2] = xc[r0 + wp];
        v[3] = xc[r1 + wm]; v[4] = xc[r1 + w]; v[5] = xc[r1 + wp];
        v[6] = xc[r2 + wm]; v[7] = xc[r2 + w]; v[8] = xc[r2 + wp];
        int q[9];
        #pragma unroll
        for (int i = 0; i < 9; ++i) {
            int qi = (int)(v[i] * 7.0f);       // trunc toward zero, like astype(int32)
            qi = qi < 0 ? 0 : qi;
            q[i] = qi > 7 ? 7 : qi;
        }
        int idx[20], m[20];
        #pragma unroll
        for (int a = 0; a < 20; ++a) {
            int d = q[PA[a]] - q[PB[a]];
            csum += d * d;
            int ad = d < 0 ? -d : d;
            hsum += __builtin_amdgcn_rcpf((float)(1 + ad));
            idx[a] = q[PA[a]] * 8 + q[PB[a]];
            m[a] = 1;
        }
        // multiplicity of each pair's bin among the 20 pairs (190 comparisons)
        #pragma unroll
        for (int a = 0; a < 20; ++a) {
            #pragma unroll
            for (int bb = a + 1; bb < 20; ++bb) {
                int e = (idx[a] == idx[bb]) ? 1 : 0;
                m[a] += e;
                m[bb] += e;
            }
        }
        #pragma unroll
        for (int a = 0; a < 20; ++a) {
            esum += m[a];
            lsum += __logf((float)m[a] * 0.05f + 1e-6f);
        }
    }

    // per-thread partial features (sum over its 4 channels)
    const float fc = (float)csum * (1.0f / 20.0f);
    const float fe = (float)esum * (1.0f / 400.0f);
    const float fn = -lsum * (1.0f / 20.0f);
    const float fh = hsum * (1.0f / 20.0f);

    __shared__ float part[256][4];
    part[t][0] = fc; part[t][1] = fe; part[t][2] = fn; part[t][3] = fh;
    __syncthreads();

    if (t < 64) {
        const int p2 = t & 15;         // pixel within block
        const int f  = t >> 4;         // feature 0..3
        float s = 0.f;
        #pragma unroll
        for (int cgi = 0; cgi < 16; ++cgi) s += part[cgi * 16 + p2][f];
        s *= (1.0f / 64.0f);           // mean over 64 channels
        const int pix2 = blockIdx.x * 16 + p2;
        const int b2 = pix2 / HW;
        const int hw2 = pix2 - b2 * HW;
        g[((size_t)(b2 * 4 + f)) * HW + hw2] = s;
    }
}

// ---------------------------------------------------------------------------
// Kernel 2: cv1 + cv2 (1x1 convs over concat(x, g), 68 -> 32 each) + BN + SiLU
// block 256 = 4 waves; lane = pixel (64/block), wave = oc-group (8 oc per wave
// for each of the two convs). Weight index is wave-uniform -> scalar loads.
// ---------------------------------------------------------------------------
__global__ __launch_bounds__(256) void stage1_kernel(
    const float* __restrict__ x, const float* __restrict__ g,
    const float* __restrict__ w1, const float* __restrict__ s1, const float* __restrict__ b1,
    const float* __restrict__ w2, const float* __restrict__ s2, const float* __restrict__ b2,
    float* __restrict__ a, float* __restrict__ bbuf) {
    const int t = threadIdx.x;
    const int lane = t & 63;
    const int wv = __builtin_amdgcn_readfirstlane(t >> 6);   // 0..3, SGPR
    const int oc0 = wv * 8;
    const int pix = blockIdx.x * 64 + lane;
    const int bi = pix / HW;
    const int hw = pix - bi * HW;
    const float* xp = x + (size_t)(bi * C) * HW + hw;
    const float* gp = g + (size_t)(bi * 4) * HW + hw;

    float acc1[8] = {0.f, 0.f, 0.f, 0.f, 0.f, 0.f, 0.f, 0.f};
    float acc2[8] = {0.f, 0.f, 0.f, 0.f, 0.f, 0.f, 0.f, 0.f};
    for (int ic = 0; ic < C; ++ic) {
        const float xv = xp[(size_t)ic * HW];
        #pragma unroll
        for (int j = 0; j < 8; ++j) {
            acc1[j] += xv * w1[(oc0 + j) * 68 + ic];
            acc2[j] += xv * w2[(oc0 + j) * 68 + ic];
        }
    }
    #pragma unroll
    for (int ic = 0; ic < 4; ++ic) {
        const float gv = gp[(size_t)ic * HW];
        #pragma unroll
        for (int j = 0; j < 8; ++j) {
            acc1[j] += gv * w1[(oc0 + j) * 68 + 64 + ic];
            acc2[j] += gv * w2[(oc0 + j) * 68 + 64 + ic];
        }
    }
    #pragma unroll
    for (int j = 0; j < 8; ++j) {
        const int oc = oc0 + j;
        a[((size_t)(bi * 32 + oc)) * HW + hw]    = silu(acc1[j] * s1[oc] + b1[oc]);
        bbuf[((size_t)(bi * 32 + oc)) * HW + hw] = silu(acc2[j] * s2[oc] + b2[oc]);
    }
}

// ---------------------------------------------------------------------------
// Kernel 3: m1 (1x1, 32 -> 16) + BN + SiLU. wave = 4 oc.
// ---------------------------------------------------------------------------
__global__ __launch_bounds__(256) void m1_kernel(
    const float* __restrict__ a, const float* __restrict__ wm,
    const float* __restrict__ sm, const float* __restrict__ bm,
    float* __restrict__ y16) {
    const int t = threadIdx.x;
    const int lane = t & 63;
    const int wv = __builtin_amdgcn_readfirstlane(t >> 6);
    const int oc0 = wv * 4;
    const int pix = blockIdx.x * 64 + lane;
    const int bi = pix / HW;
    const int hw = pix - bi * HW;
    const float* ap = a + (size_t)(bi * 32) * HW + hw;

    float acc[4] = {0.f, 0.f, 0.f, 0.f};
    for (int ic = 0; ic < 32; ++ic) {
        const float av = ap[(size_t)ic * HW];
        #pragma unroll
        for (int j = 0; j < 4; ++j) acc[j] += av * wm[(oc0 + j) * 32 + ic];
    }
    #pragma unroll
    for (int j = 0; j < 4; ++j) {
        const int oc = oc0 + j;
        y16[((size_t)(bi * 16 + oc)) * HW + hw] = silu(acc[j] * sm[oc] + bm[oc]);
    }
}

// ---------------------------------------------------------------------------
// Kernel 4: m2 (3x3, 16 -> 32, zero pad 1) + BN + SiLU + residual add into a.
// wave = 8 oc.
// ---------------------------------------------------------------------------
__global__ __launch_bounds__(256) void m2_kernel(
    const float* __restrict__ y16, const float* __restrict__ wm,
    const float* __restrict__ sm, const float* __restrict__ bm,
    float* __restrict__ a) {
    const int t = threadIdx.x;
    const int lane = t & 63;
    const int wv = __builtin_amdgcn_readfirstlane(t >> 6);
    const int oc0 = wv * 8;
    const int pix = blockIdx.x * 64 + lane;
    const int bi = pix / HW;
    const int hw = pix - bi * HW;
    const int h = hw / W;
    const int w = hw - h * W;
    const float* yp = y16 + (size_t)(bi * 16) * HW;

    float acc[8] = {0.f, 0.f, 0.f, 0.f, 0.f, 0.f, 0.f, 0.f};
    for (int ic = 0; ic < 16; ++ic) {
        #pragma unroll
        for (int kh = 0; kh < 3; ++kh) {
            const int rr = h + kh - 1;
            const bool rin = (rr >= 0) && (rr < H);
            #pragma unroll
            for (int kw = 0; kw < 3; ++kw) {
                const int cc = w + kw - 1;
                const bool in = rin && (cc >= 0) && (cc < W);
                const float yv = in ? yp[(size_t)ic * HW + rr * W + cc] : 0.0f;
                #pragma unroll
                for (int j = 0; j < 8; ++j)
                    acc[j] += yv * wm[(((oc0 + j) * 16 + ic) * 3 + kh) * 3 + kw];
            }
        }
    }
    #pragma unroll
    for (int j = 0; j < 8; ++j) {
        const int oc = oc0 + j;
        const size_t o = ((size_t)(bi * 32 + oc)) * HW + hw;
        a[o] = a[o] + silu(acc[j] * sm[oc] + bm[oc]);
    }
}

// ---------------------------------------------------------------------------
// Kernel 5: cv3 (1x1 over concat(a', b), 64 -> 64) + BN + SiLU -> out.
// wave = 16 oc.
// ---------------------------------------------------------------------------
__global__ __launch_bounds__(256) void cv3_kernel(
    const float* __restrict__ a, const float* __restrict__ bbuf,
    const float* __restrict__ wc, const float* __restrict__ sc,
    const float* __restrict__ bc, float* __restrict__ out) {
    const int t = threadIdx.x;
    const int lane = t & 63;
    const int wv = __builtin_amdgcn_readfirstlane(t >> 6);
    const int oc0 = wv * 16;
    const int pix = blockIdx.x * 64 + lane;
    const int bi = pix / HW;
    const int hw = pix - bi * HW;
    const float* ap = a + (size_t)(bi * 32) * HW + hw;
    const float* bp = bbuf + (size_t)(bi * 32) * HW + hw;

    float acc[16];
    #pragma unroll
    for (int j = 0; j < 16; ++j) acc[j] = 0.f;
    for (int ic = 0; ic < 32; ++ic) {
        const float av = ap[(size_t)ic * HW];
        #pragma unroll
        for (int j = 0; j < 16; ++j) acc[j] += av * wc[(oc0 + j) * 64 + ic];
    }
    for (int ic = 0; ic < 32; ++ic) {
        const float bv = bp[(size_t)ic * HW];
        #pragma unroll
        for (int j = 0; j < 16; ++j) acc[j] += bv * wc[(oc0 + j) * 64 + 32 + ic];
    }
    #pragma unroll
    for (int j = 0; j < 16; ++j) {
        const int oc = oc0 + j;
        out[((size_t)(bi * 64 + oc)) * HW + hw] = silu(acc[j] * sc[oc] + bc[oc]);
    }
}

// ---------------------------------------------------------------------------
extern "C" void kernel_launch(void* const* d_in, const int* in_sizes, int n_in,
                              void* d_out, int out_size, void* d_ws, size_t ws_size,
                              hipStream_t stream) {
    const float* x    = (const float*)d_in[0];
    const float* cv1w = (const float*)d_in[1];
    const float* cv1s = (const float*)d_in[2];
    const float* cv1b = (const float*)d_in[3];
    const float* cv2w = (const float*)d_in[4];
    const float* cv2s = (const float*)d_in[5];
    const float* cv2b = (const float*)d_in[6];
    const float* m1w  = (const float*)d_in[7];
    const float* m1s  = (const float*)d_in[8];
    const float* m1b  = (const float*)d_in[9];
    const float* m2w  = (const float*)d_in[10];
    const float* m2s  = (const float*)d_in[11];
    const float* m2b  = (const float*)d_in[12];
    const float* cv3w = (const float*)d_in[13];
    const float* cv3s = (const float*)d_in[14];
    const float* cv3b = (const float*)d_in[15];

    float* ws   = (float*)d_ws;
    float* g    = ws;                 // 4*4*6400      = 102400 floats
    float* y16  = ws + 102400;        // 4*16*6400     = 409600 floats
    float* a    = ws + 512000;        // 4*32*6400     = 819200 floats
    float* bbuf = ws + 1331200;       // 4*32*6400     = 819200 floats (end 2150400)

    glcm_kernel<<<NPIX / 16, 256, 0, stream>>>(x, g);
    stage1_kernel<<<NPIX / 64, 256, 0, stream>>>(x, g, cv1w, cv1s, cv1b,
                                                 cv2w, cv2s, cv2b, a, bbuf);
    m1_kernel<<<NPIX / 64, 256, 0, stream>>>(a, m1w, m1s, m1b, y16);
    m2_kernel<<<NPIX / 64, 256, 0, stream>>>(y16, m2w, m2s, m2b, a);
    cv3_kernel<<<NPIX / 64, 256, 0, stream>>>(a, bbuf, cv3w, cv3s, cv3b,
                                              (float*)d_out);
}

// Round 2
// 74.082 us; speedup vs baseline: 1.4180x; 1.4180x over previous
//
#include <hip/hip_runtime.h>
#include <math.h>

constexpr int B = 4, C = 64, H = 80, W = 80;
constexpr int HW = H * W;            // 6400
constexpr int NPIX = B * HW;         // 25600

static __device__ __forceinline__ float silu(float v) {
    float e = __expf(-v);
    return v * __builtin_amdgcn_rcpf(1.0f + e);
}

// packed compare-exchange: both u16 halves sorted independently (2 channels)
static __device__ __forceinline__ void ce(unsigned &x, unsigned &y) {
    unsigned mn, mx;
    asm("v_pk_min_u16 %0, %2, %3\n\t"
        "v_pk_max_u16 %1, %2, %3"
        : "=&v"(mn), "=v"(mx) : "v"(x), "v"(y));
    x = mn; y = mx;
}

// ---------------------------------------------------------------------------
// Kernel 1: GLCM features. thread = (pixel, 2 channels).
// block 256 = 8 pixels x 32 channel-pairs. grid = 25600/8 = 3200.
// Per (pixel,channel): 20 co-occurrence pair bins; sort (packed Batcher
// network) -> run-length scans give multiplicity m_a.
//   contrast = sum d^2 / 20, homog = sum 1/(1+|d|) / 20
//   energy   = (20 + 2*sum p_fwd) / 400
//   entropy  = -(20*log(0.05) + log(prod m_a)) / 20
// ---------------------------------------------------------------------------
__global__ __launch_bounds__(256) void glcm_kernel(const float* __restrict__ x,
                                                   float* __restrict__ g) {
    const int t = threadIdx.x;
    const int pxl = t & 7;               // 0..7
    const int grp = t >> 3;              // 0..31 (channel pair)
    const int pix = blockIdx.x * 8 + pxl;
    const int b = pix / HW;
    const int hw = pix - b * HW;
    const int h = hw / W;
    const int w = hw - h * W;
    const int hm = h > 0 ? h - 1 : 0;
    const int hp = h < H - 1 ? h + 1 : H - 1;
    const int wm = w > 0 ? w - 1 : 0;
    const int wp = w < W - 1 ? w + 1 : W - 1;
    const int o[9] = {hm * W + wm, hm * W + w, hm * W + wp,
                      h  * W + wm, h  * W + w, h  * W + wp,
                      hp * W + wm, hp * W + w, hp * W + wp};
    const float* c0 = x + (size_t)(b * C + grp * 2) * HW;
    const float* c1 = c0 + HW;

    int q0[9], q1[9];
    #pragma unroll
    for (int k = 0; k < 9; ++k) {
        int a0 = (int)(c0[o[k]] * 7.0f);
        int a1 = (int)(c1[o[k]] * 7.0f);
        a0 = a0 < 0 ? 0 : a0; q0[k] = a0 > 7 ? 7 : a0;
        a1 = a1 < 0 ? 0 : a1; q1[k] = a1 > 7 ? 7 : a1;
    }

    static constexpr int PA[20] = {0,1,3,4,6,7, 0,1,2,3,4,5, 0,1,3,4, 1,2,4,5};
    static constexpr int PB[20] = {1,2,4,5,7,8, 3,4,5,6,7,8, 4,5,7,8, 3,4,6,7};

    int csum = 0;
    float hsum = 0.f;
    unsigned key[20];
    #pragma unroll
    for (int a = 0; a < 20; ++a) {
        const int d0 = q0[PA[a]] - q0[PB[a]];
        const int d1 = q1[PA[a]] - q1[PB[a]];
        csum += d0 * d0 + d1 * d1;
        const int a0 = d0 < 0 ? -d0 : d0;
        const int a1 = d1 < 0 ? -d1 : d1;
        hsum += __builtin_amdgcn_rcpf((float)(1 + a0))
              + __builtin_amdgcn_rcpf((float)(1 + a1));
        key[a] = (unsigned)((q0[PA[a]] * 8 + q0[PB[a]])
                          | ((q1[PA[a]] * 8 + q1[PB[a]]) << 16));
    }

    // Batcher odd-even mergesort for n=32, pruned to the low 20 slots
    // (virtual +infinity padding at 20..31 never moves down -> prune valid).
    #pragma unroll
    for (int p = 1; p < 32; p <<= 1) {
        #pragma unroll
        for (int k = p; k >= 1; k >>= 1) {
            const int jm = k % p;
            #pragma unroll
            for (int lo = 0; lo < 20; ++lo) {
                const int hi = lo + k;
                if (hi < 20 && lo >= jm && ((lo - jm) % (2 * k)) < k &&
                    (lo / (2 * p)) == (hi / (2 * p))) {
                    ce(key[lo], key[hi]);
                }
            }
        }
    }

    float psum = 0.f, lsum = 0.f;
    #pragma unroll
    for (int hh = 0; hh < 2; ++hh) {
        const int sh = hh * 16;
        float p_[20];
        float pc = 0.f;
        p_[0] = 0.f;
        unsigned prev = (key[0] >> sh) & 0xFFFFu;
        #pragma unroll
        for (int a = 1; a < 20; ++a) {
            const unsigned cur = (key[a] >> sh) & 0xFFFFu;
            pc = (cur == prev) ? pc + 1.f : 0.f;
            p_[a] = pc;
            psum += pc;
            prev = cur;
        }
        // backward: r = run-position from the end; m = p + r + 1
        float r = 0.f;
        float prod = p_[19] + 1.f;
        prev = (key[19] >> sh) & 0xFFFFu;
        #pragma unroll
        for (int a = 18; a >= 0; --a) {
            const unsigned cur = (key[a] >> sh) & 0xFFFFu;
            r = (cur == prev) ? r + 1.f : 0.f;
            prod *= (p_[a] + r + 1.f);
            prev = cur;
        }
        lsum += __logf(prod);
    }

    // partial features summed over this thread's 2 channels
    float fc = (float)csum * (1.f / 20.f);
    float fe = (psum * 2.f + 40.f) * (1.f / 400.f);
    float fn = -(lsum + 40.f * -2.9957322736f /*log(0.05)*/) * (1.f / 20.f);
    float fh = hsum * (1.f / 20.f);

    // reduce over 8 channel-pairs within the wave (lane bits 3..5)
    #pragma unroll
    for (int m = 8; m < 64; m <<= 1) {
        fc += __shfl_xor(fc, m);
        fe += __shfl_xor(fe, m);
        fn += __shfl_xor(fn, m);
        fh += __shfl_xor(fh, m);
    }
    __shared__ float red[4][8][4];
    const int wv = t >> 6;
    if ((t & 63) < 8) {
        red[wv][pxl][0] = fc; red[wv][pxl][1] = fe;
        red[wv][pxl][2] = fn; red[wv][pxl][3] = fh;
    }
    __syncthreads();
    if (t < 32) {
        const int p2 = t >> 2, f = t & 3;
        float s = red[0][p2][f] + red[1][p2][f] + red[2][p2][f] + red[3][p2][f];
        s *= (1.f / 64.f);
        const int pix2 = blockIdx.x * 8 + p2;
        const int b2 = pix2 / HW;
        const int hw2 = pix2 - b2 * HW;
        g[((size_t)(b2 * 4 + f)) * HW + hw2] = s;
    }
}

// ---------------------------------------------------------------------------
// Kernel 2: cv1 + cv2 (1x1, 68->32 each) + BN + SiLU, then m1 (1x1, 32->16)
// fused via an LDS tile of cv1's output. block 256 = 4 waves x 64 pixels.
// Wave w: 8 oc of cv1+cv2; after barrier, 4 oc of m1.
// ---------------------------------------------------------------------------
__global__ __launch_bounds__(256) void stage1_kernel(
    const float* __restrict__ x, const float* __restrict__ g,
    const float* __restrict__ w1, const float* __restrict__ s1, const float* __restrict__ b1,
    const float* __restrict__ w2, const float* __restrict__ s2, const float* __restrict__ b2,
    const float* __restrict__ wm1, const float* __restrict__ sm1, const float* __restrict__ bm1,
    float* __restrict__ a, float* __restrict__ bbuf, float* __restrict__ y16) {
    __shared__ float aT[32][64];
    const int t = threadIdx.x;
    const int lane = t & 63;
    const int wv = __builtin_amdgcn_readfirstlane(t >> 6);
    const int oc0 = wv * 8;
    const int pix = blockIdx.x * 64 + lane;
    const int bi = pix / HW;
    const int hw = pix - bi * HW;
    const float* xp = x + (size_t)(bi * C) * HW + hw;
    const float* gp = g + (size_t)(bi * 4) * HW + hw;

    float acc1[8] = {0.f, 0.f, 0.f, 0.f, 0.f, 0.f, 0.f, 0.f};
    float acc2[8] = {0.f, 0.f, 0.f, 0.f, 0.f, 0.f, 0.f, 0.f};
    for (int ic = 0; ic < C; ++ic) {
        const float xv = xp[(size_t)ic * HW];
        #pragma unroll
        for (int j = 0; j < 8; ++j) {
            acc1[j] += xv * w1[(oc0 + j) * 68 + ic];
            acc2[j] += xv * w2[(oc0 + j) * 68 + ic];
        }
    }
    #pragma unroll
    for (int ic = 0; ic < 4; ++ic) {
        const float gv = gp[(size_t)ic * HW];
        #pragma unroll
        for (int j = 0; j < 8; ++j) {
            acc1[j] += gv * w1[(oc0 + j) * 68 + 64 + ic];
            acc2[j] += gv * w2[(oc0 + j) * 68 + 64 + ic];
        }
    }
    #pragma unroll
    for (int j = 0; j < 8; ++j) {
        const int oc = oc0 + j;
        const float v1 = silu(acc1[j] * s1[oc] + b1[oc]);
        a[((size_t)(bi * 32 + oc)) * HW + hw] = v1;
        aT[oc][lane] = v1;
        bbuf[((size_t)(bi * 32 + oc)) * HW + hw] = silu(acc2[j] * s2[oc] + b2[oc]);
    }
    __syncthreads();
    // m1: wave w computes oc [4w, 4w+4)
    const int om0 = wv * 4;
    float accm[4] = {0.f, 0.f, 0.f, 0.f};
    for (int ic = 0; ic < 32; ++ic) {
        const float av = aT[ic][lane];
        #pragma unroll
        for (int j = 0; j < 4; ++j) accm[j] += av * wm1[(om0 + j) * 32 + ic];
    }
    #pragma unroll
    for (int j = 0; j < 4; ++j) {
        const int oc = om0 + j;
        y16[((size_t)(bi * 16 + oc)) * HW + hw] = silu(accm[j] * sm1[oc] + bm1[oc]);
    }
}

// ---------------------------------------------------------------------------
// Kernel 3: m2 (3x3, 16->32, pad 1) + BN + SiLU + residual (a), then cv3
// (1x1 over concat(a', b), 64->64) fused via LDS tile of a'.
// block 256 = 4 waves x 64 pixels. Wave w: 8 oc of m2, then 16 oc of cv3.
// ---------------------------------------------------------------------------
__global__ __launch_bounds__(256) void m2cv3_kernel(
    const float* __restrict__ y16, const float* __restrict__ a,
    const float* __restrict__ bbuf,
    const float* __restrict__ wm2, const float* __restrict__ sm2, const float* __restrict__ bm2,
    const float* __restrict__ wc, const float* __restrict__ sc, const float* __restrict__ bc,
    float* __restrict__ out) {
    __shared__ float a2[32][64];
    const int t = threadIdx.x;
    const int lane = t & 63;
    const int wv = __builtin_amdgcn_readfirstlane(t >> 6);
    const int oc0 = wv * 8;
    const int pix = blockIdx.x * 64 + lane;
    const int bi = pix / HW;
    const int hw = pix - bi * HW;
    const int h = hw / W;
    const int w = hw - h * W;
    const float* yp = y16 + (size_t)(bi * 16) * HW;

    float acc[8] = {0.f, 0.f, 0.f, 0.f, 0.f, 0.f, 0.f, 0.f};
    for (int ic = 0; ic < 16; ++ic) {
        #pragma unroll
        for (int kh = 0; kh < 3; ++kh) {
            const int rr = h + kh - 1;
            const bool rin = (rr >= 0) && (rr < H);
            #pragma unroll
            for (int kw = 0; kw < 3; ++kw) {
                const int cc = w + kw - 1;
                const bool in = rin && (cc >= 0) && (cc < W);
                const float yv = in ? yp[(size_t)ic * HW + rr * W + cc] : 0.0f;
                #pragma unroll
                for (int j = 0; j < 8; ++j)
                    acc[j] += yv * wm2[(((oc0 + j) * 16 + ic) * 3 + kh) * 3 + kw];
            }
        }
    }
    #pragma unroll
    for (int j = 0; j < 8; ++j) {
        const int oc = oc0 + j;
        const float v = a[((size_t)(bi * 32 + oc)) * HW + hw]
                      + silu(acc[j] * sm2[oc] + bm2[oc]);
        a2[oc][lane] = v;
    }
    __syncthreads();
    // cv3: wave w computes oc [16w, 16w+16)
    const int oc3 = wv * 16;
    const float* bp = bbuf + (size_t)(bi * 32) * HW + hw;
    float acc3[16];
    #pragma unroll
    for (int j = 0; j < 16; ++j) acc3[j] = 0.f;
    for (int ic = 0; ic < 32; ++ic) {
        const float av = a2[ic][lane];
        #pragma unroll
        for (int j = 0; j < 16; ++j) acc3[j] += av * wc[(oc3 + j) * 64 + ic];
    }
    for (int ic = 0; ic < 32; ++ic) {
        const float bv = bp[(size_t)ic * HW];
        #pragma unroll
        for (int j = 0; j < 16; ++j) acc3[j] += bv * wc[(oc3 + j) * 64 + 32 + ic];
    }
    #pragma unroll
    for (int j = 0; j < 16; ++j) {
        const int oc = oc3 + j;
        out[((size_t)(bi * 64 + oc)) * HW + hw] = silu(acc3[j] * sc[oc] + bc[oc]);
    }
}

// ---------------------------------------------------------------------------
extern "C" void kernel_launch(void* const* d_in, const int* in_sizes, int n_in,
                              void* d_out, int out_size, void* d_ws, size_t ws_size,
                              hipStream_t stream) {
    const float* x    = (const float*)d_in[0];
    const float* cv1w = (const float*)d_in[1];
    const float* cv1s = (const float*)d_in[2];
    const float* cv1b = (const float*)d_in[3];
    const float* cv2w = (const float*)d_in[4];
    const float* cv2s = (const float*)d_in[5];
    const float* cv2b = (const float*)d_in[6];
    const float* m1w  = (const float*)d_in[7];
    const float* m1s  = (const float*)d_in[8];
    const float* m1b  = (const float*)d_in[9];
    const float* m2w  = (const float*)d_in[10];
    const float* m2s  = (const float*)d_in[11];
    const float* m2b  = (const float*)d_in[12];
    const float* cv3w = (const float*)d_in[13];
    const float* cv3s = (const float*)d_in[14];
    const float* cv3b = (const float*)d_in[15];

    float* ws   = (float*)d_ws;
    float* g    = ws;                 // 4*4*6400   = 102400 floats
    float* a    = ws + 102400;        // 4*32*6400  = 819200
    float* bbuf = ws + 921600;        // 4*32*6400  = 819200
    float* y16  = ws + 1740800;       // 4*16*6400  = 409600 (end 2150400)

    glcm_kernel<<<NPIX / 8, 256, 0, stream>>>(x, g);
    stage1_kernel<<<NPIX / 64, 256, 0, stream>>>(x, g, cv1w, cv1s, cv1b,
                                                 cv2w, cv2s, cv2b,
                                                 m1w, m1s, m1b, a, bbuf, y16);
    m2cv3_kernel<<<NPIX / 64, 256, 0, stream>>>(y16, a, bbuf, m2w, m2s, m2b,
                                                cv3w, cv3s, cv3b, (float*)d_out);
}

// Round 3
// 64.747 us; speedup vs baseline: 1.6224x; 1.1442x over previous
//
#include <hip/hip_runtime.h>
#include <math.h>

constexpr int B = 4, C = 64, H = 80, W = 80;
constexpr int HW = H * W;            // 6400
constexpr int NPIX = B * HW;         // 25600

static __device__ __forceinline__ float silu(float v) {
    float e = __expf(-v);
    return v * __builtin_amdgcn_rcpf(1.0f + e);
}

// packed compare-exchange: both u16 halves sorted independently (2 channels)
static __device__ __forceinline__ void ce(unsigned &x, unsigned &y) {
    unsigned mn, mx;
    asm("v_pk_min_u16 %0, %2, %3\n\t"
        "v_pk_max_u16 %1, %2, %3"
        : "=&v"(mn), "=v"(mx) : "v"(x), "v"(y));
    x = mn; y = mx;
}

// ---------------------------------------------------------------------------
// Kernel 1: GLCM features. thread = (pixel, 2 channels).
// block 256 = 8 pixels x 32 channel-pairs. grid = 25600/8 = 3200.
// Per (pixel,channel): 20 co-occurrence pair bins; sort (packed Batcher
// network) -> run-length scans give multiplicity m_a.
//   contrast = sum d^2 / 20, homog = sum 1/(1+|d|) / 20
//   energy   = (20 + 2*sum p_fwd) / 400
//   entropy  = -(20*log(0.05) + log(prod m_a)) / 20
// ---------------------------------------------------------------------------
__global__ __launch_bounds__(256) void glcm_kernel(const float* __restrict__ x,
                                                   float* __restrict__ g) {
    const int t = threadIdx.x;
    const int pxl = t & 7;               // 0..7
    const int grp = t >> 3;              // 0..31 (channel pair)
    const int pix = blockIdx.x * 8 + pxl;
    const int b = pix / HW;
    const int hw = pix - b * HW;
    const int h = hw / W;
    const int w = hw - h * W;
    const int hm = h > 0 ? h - 1 : 0;
    const int hp = h < H - 1 ? h + 1 : H - 1;
    const int wm = w > 0 ? w - 1 : 0;
    const int wp = w < W - 1 ? w + 1 : W - 1;
    const int o[9] = {hm * W + wm, hm * W + w, hm * W + wp,
                      h  * W + wm, h  * W + w, h  * W + wp,
                      hp * W + wm, hp * W + w, hp * W + wp};
    const float* c0 = x + (size_t)(b * C + grp * 2) * HW;
    const float* c1 = c0 + HW;

    int q0[9], q1[9];
    #pragma unroll
    for (int k = 0; k < 9; ++k) {
        int a0 = (int)(c0[o[k]] * 7.0f);
        int a1 = (int)(c1[o[k]] * 7.0f);
        a0 = a0 < 0 ? 0 : a0; q0[k] = a0 > 7 ? 7 : a0;
        a1 = a1 < 0 ? 0 : a1; q1[k] = a1 > 7 ? 7 : a1;
    }

    static constexpr int PA[20] = {0,1,3,4,6,7, 0,1,2,3,4,5, 0,1,3,4, 1,2,4,5};
    static constexpr int PB[20] = {1,2,4,5,7,8, 3,4,5,6,7,8, 4,5,7,8, 3,4,6,7};

    int csum = 0;
    float hsum = 0.f;
    unsigned key[20];
    #pragma unroll
    for (int a = 0; a < 20; ++a) {
        const int d0 = q0[PA[a]] - q0[PB[a]];
        const int d1 = q1[PA[a]] - q1[PB[a]];
        csum += d0 * d0 + d1 * d1;
        const int a0 = d0 < 0 ? -d0 : d0;
        const int a1 = d1 < 0 ? -d1 : d1;
        hsum += __builtin_amdgcn_rcpf((float)(1 + a0))
              + __builtin_amdgcn_rcpf((float)(1 + a1));
        key[a] = (unsigned)((q0[PA[a]] * 8 + q0[PB[a]])
                          | ((q1[PA[a]] * 8 + q1[PB[a]]) << 16));
    }

    // Batcher odd-even mergesort for n=32, pruned to the low 20 slots
    // (virtual +infinity padding at 20..31 never moves down -> prune valid).
    #pragma unroll
    for (int p = 1; p < 32; p <<= 1) {
        #pragma unroll
        for (int k = p; k >= 1; k >>= 1) {
            const int jm = k % p;
            #pragma unroll
            for (int lo = 0; lo < 20; ++lo) {
                const int hi = lo + k;
                if (hi < 20 && lo >= jm && ((lo - jm) % (2 * k)) < k &&
                    (lo / (2 * p)) == (hi / (2 * p))) {
                    ce(key[lo], key[hi]);
                }
            }
        }
    }

    float psum = 0.f, lsum = 0.f;
    #pragma unroll
    for (int hh = 0; hh < 2; ++hh) {
        const int sh = hh * 16;
        float p_[20];
        float pc = 0.f;
        p_[0] = 0.f;
        unsigned prev = (key[0] >> sh) & 0xFFFFu;
        #pragma unroll
        for (int a = 1; a < 20; ++a) {
            const unsigned cur = (key[a] >> sh) & 0xFFFFu;
            pc = (cur == prev) ? pc + 1.f : 0.f;
            p_[a] = pc;
            psum += pc;
            prev = cur;
        }
        // backward: r = run-position from the end; m = p + r + 1
        float r = 0.f;
        float prod = p_[19] + 1.f;
        prev = (key[19] >> sh) & 0xFFFFu;
        #pragma unroll
        for (int a = 18; a >= 0; --a) {
            const unsigned cur = (key[a] >> sh) & 0xFFFFu;
            r = (cur == prev) ? r + 1.f : 0.f;
            prod *= (p_[a] + r + 1.f);
            prev = cur;
        }
        lsum += __logf(prod);
    }

    // partial features summed over this thread's 2 channels
    float fc = (float)csum * (1.f / 20.f);
    float fe = (psum * 2.f + 40.f) * (1.f / 400.f);
    float fn = -(lsum + 40.f * -2.9957322736f /*log(0.05)*/) * (1.f / 20.f);
    float fh = hsum * (1.f / 20.f);

    // reduce over 8 channel-pairs within the wave (lane bits 3..5)
    #pragma unroll
    for (int m = 8; m < 64; m <<= 1) {
        fc += __shfl_xor(fc, m);
        fe += __shfl_xor(fe, m);
        fn += __shfl_xor(fn, m);
        fh += __shfl_xor(fh, m);
    }
    __shared__ float red[4][8][4];
    const int wv = t >> 6;
    if ((t & 63) < 8) {
        red[wv][pxl][0] = fc; red[wv][pxl][1] = fe;
        red[wv][pxl][2] = fn; red[wv][pxl][3] = fh;
    }
    __syncthreads();
    if (t < 32) {
        const int p2 = t >> 2, f = t & 3;
        float s = red[0][p2][f] + red[1][p2][f] + red[2][p2][f] + red[3][p2][f];
        s *= (1.f / 64.f);
        const int pix2 = blockIdx.x * 8 + p2;
        const int b2 = pix2 / HW;
        const int hw2 = pix2 - b2 * HW;
        g[((size_t)(b2 * 4 + f)) * HW + hw2] = s;
    }
}

// ---------------------------------------------------------------------------
// Kernel 2: cv1 + cv2 (1x1, 68->32 each) + BN + SiLU, then m1 (1x1, 32->16)
// fused via an LDS tile of cv1's output. block 512 = 8 waves x 64 pixels.
// Wave w: 4 oc of cv1 AND 4 oc of cv2; after barrier, 2 oc of m1.
// (8 waves/block doubles waves/SIMD vs the 4-wave version: latency-bound.)
// ---------------------------------------------------------------------------
__global__ __launch_bounds__(512) void stage1_kernel(
    const float* __restrict__ x, const float* __restrict__ g,
    const float* __restrict__ w1, const float* __restrict__ s1, const float* __restrict__ b1,
    const float* __restrict__ w2, const float* __restrict__ s2, const float* __restrict__ b2,
    const float* __restrict__ wm1, const float* __restrict__ sm1, const float* __restrict__ bm1,
    float* __restrict__ a, float* __restrict__ bbuf, float* __restrict__ y16) {
    __shared__ float aT[32][64];
    const int t = threadIdx.x;
    const int lane = t & 63;
    const int wv = __builtin_amdgcn_readfirstlane(t >> 6);   // 0..7
    const int oc0 = wv * 4;
    const int pix = blockIdx.x * 64 + lane;
    const int bi = pix / HW;
    const int hw = pix - bi * HW;
    const float* xp = x + (size_t)(bi * C) * HW + hw;
    const float* gp = g + (size_t)(bi * 4) * HW + hw;

    float acc1[4] = {0.f, 0.f, 0.f, 0.f};
    float acc2[4] = {0.f, 0.f, 0.f, 0.f};
    #pragma unroll 8
    for (int ic = 0; ic < C; ++ic) {
        const float xv = xp[(size_t)ic * HW];
        #pragma unroll
        for (int j = 0; j < 4; ++j) {
            acc1[j] += xv * w1[(oc0 + j) * 68 + ic];
            acc2[j] += xv * w2[(oc0 + j) * 68 + ic];
        }
    }
    #pragma unroll
    for (int ic = 0; ic < 4; ++ic) {
        const float gv = gp[(size_t)ic * HW];
        #pragma unroll
        for (int j = 0; j < 4; ++j) {
            acc1[j] += gv * w1[(oc0 + j) * 68 + 64 + ic];
            acc2[j] += gv * w2[(oc0 + j) * 68 + 64 + ic];
        }
    }
    #pragma unroll
    for (int j = 0; j < 4; ++j) {
        const int oc = oc0 + j;
        const float v1 = silu(acc1[j] * s1[oc] + b1[oc]);
        a[((size_t)(bi * 32 + oc)) * HW + hw] = v1;
        aT[oc][lane] = v1;
        bbuf[((size_t)(bi * 32 + oc)) * HW + hw] = silu(acc2[j] * s2[oc] + b2[oc]);
    }
    __syncthreads();
    // m1: wave w computes oc [2w, 2w+2)
    const int om0 = wv * 2;
    float accm[2] = {0.f, 0.f};
    #pragma unroll 8
    for (int ic = 0; ic < 32; ++ic) {
        const float av = aT[ic][lane];
        #pragma unroll
        for (int j = 0; j < 2; ++j) accm[j] += av * wm1[(om0 + j) * 32 + ic];
    }
    #pragma unroll
    for (int j = 0; j < 2; ++j) {
        const int oc = om0 + j;
        y16[((size_t)(bi * 16 + oc)) * HW + hw] = silu(accm[j] * sm1[oc] + bm1[oc]);
    }
}

// ---------------------------------------------------------------------------
// Kernel 3: m2 (3x3, 16->32, pad 1) + BN + SiLU + residual (a), then cv3
// (1x1 over concat(a', b), 64->64) fused via LDS tile of a'.
// block 512 = 8 waves x 64 pixels. Wave w: 4 oc of m2, then 8 oc of cv3.
// ---------------------------------------------------------------------------
__global__ __launch_bounds__(512) void m2cv3_kernel(
    const float* __restrict__ y16, const float* __restrict__ a,
    const float* __restrict__ bbuf,
    const float* __restrict__ wm2, const float* __restrict__ sm2, const float* __restrict__ bm2,
    const float* __restrict__ wc, const float* __restrict__ sc, const float* __restrict__ bc,
    float* __restrict__ out) {
    __shared__ float a2[32][64];
    const int t = threadIdx.x;
    const int lane = t & 63;
    const int wv = __builtin_amdgcn_readfirstlane(t >> 6);   // 0..7
    const int oc0 = wv * 4;
    const int pix = blockIdx.x * 64 + lane;
    const int bi = pix / HW;
    const int hw = pix - bi * HW;
    const int h = hw / W;
    const int w = hw - h * W;
    const float* yp = y16 + (size_t)(bi * 16) * HW;

    float acc[4] = {0.f, 0.f, 0.f, 0.f};
    for (int ic = 0; ic < 16; ++ic) {
        #pragma unroll
        for (int kh = 0; kh < 3; ++kh) {
            const int rr = h + kh - 1;
            const bool rin = (rr >= 0) && (rr < H);
            #pragma unroll
            for (int kw = 0; kw < 3; ++kw) {
                const int cc = w + kw - 1;
                const bool in = rin && (cc >= 0) && (cc < W);
                const float yv = in ? yp[(size_t)ic * HW + rr * W + cc] : 0.0f;
                #pragma unroll
                for (int j = 0; j < 4; ++j)
                    acc[j] += yv * wm2[(((oc0 + j) * 16 + ic) * 3 + kh) * 3 + kw];
            }
        }
    }
    #pragma unroll
    for (int j = 0; j < 4; ++j) {
        const int oc = oc0 + j;
        const float v = a[((size_t)(bi * 32 + oc)) * HW + hw]
                      + silu(acc[j] * sm2[oc] + bm2[oc]);
        a2[oc][lane] = v;
    }
    __syncthreads();
    // cv3: wave w computes oc [8w, 8w+8)
    const int oc3 = wv * 8;
    const float* bp = bbuf + (size_t)(bi * 32) * HW + hw;
    float acc3[8];
    #pragma unroll
    for (int j = 0; j < 8; ++j) acc3[j] = 0.f;
    #pragma unroll 8
    for (int ic = 0; ic < 32; ++ic) {
        const float av = a2[ic][lane];
        #pragma unroll
        for (int j = 0; j < 8; ++j) acc3[j] += av * wc[(oc3 + j) * 64 + ic];
    }
    #pragma unroll 8
    for (int ic = 0; ic < 32; ++ic) {
        const float bv = bp[(size_t)ic * HW];
        #pragma unroll
        for (int j = 0; j < 8; ++j) acc3[j] += bv * wc[(oc3 + j) * 64 + 32 + ic];
    }
    #pragma unroll
    for (int j = 0; j < 8; ++j) {
        const int oc = oc3 + j;
        out[((size_t)(bi * 64 + oc)) * HW + hw] = silu(acc3[j] * sc[oc] + bc[oc]);
    }
}

// ---------------------------------------------------------------------------
extern "C" void kernel_launch(void* const* d_in, const int* in_sizes, int n_in,
                              void* d_out, int out_size, void* d_ws, size_t ws_size,
                              hipStream_t stream) {
    const float* x    = (const float*)d_in[0];
    const float* cv1w = (const float*)d_in[1];
    const float* cv1s = (const float*)d_in[2];
    const float* cv1b = (const float*)d_in[3];
    const float* cv2w = (const float*)d_in[4];
    const float* cv2s = (const float*)d_in[5];
    const float* cv2b = (const float*)d_in[6];
    const float* m1w  = (const float*)d_in[7];
    const float* m1s  = (const float*)d_in[8];
    const float* m1b  = (const float*)d_in[9];
    const float* m2w  = (const float*)d_in[10];
    const float* m2s  = (const float*)d_in[11];
    const float* m2b  = (const float*)d_in[12];
    const float* cv3w = (const float*)d_in[13];
    const float* cv3s = (const float*)d_in[14];
    const float* cv3b = (const float*)d_in[15];

    float* ws   = (float*)d_ws;
    float* g    = ws;                 // 4*4*6400   = 102400 floats
    float* a    = ws + 102400;        // 4*32*6400  = 819200
    float* bbuf = ws + 921600;        // 4*32*6400  = 819200
    float* y16  = ws + 1740800;       // 4*16*6400  = 409600 (end 2150400)

    glcm_kernel<<<NPIX / 8, 256, 0, stream>>>(x, g);
    stage1_kernel<<<NPIX / 64, 512, 0, stream>>>(x, g, cv1w, cv1s, cv1b,
                                                 cv2w, cv2s, cv2b,
                                                 m1w, m1s, m1b, a, bbuf, y16);
    m2cv3_kernel<<<NPIX / 64, 512, 0, stream>>>(y16, a, bbuf, m2w, m2s, m2b,
                                                cv3w, cv3s, cv3b, (float*)d_out);
}